// Round 6
// baseline (231.582 us; speedup 1.0000x reference)
//
#include <hip/hip_runtime.h>
#include <math.h>

typedef _Float16 half8  __attribute__((ext_vector_type(8)));
typedef _Float16 half2v __attribute__((ext_vector_type(2)));
typedef float    float4v __attribute__((ext_vector_type(4)));

constexpr int T_ = 1 << 18;            // hash table size per level
constexpr unsigned TMASK = T_ - 1;
constexpr unsigned PRIME = 2654435761u;
constexpr int HP = 72;                 // H row pitch in f16 (64 + 8 pad: bank-spread)

// ws layout:
//   [0, 22528)      : 22 W-fragments (f16), frag f: 64 lanes x 8 halfs
//   [22528, 23360)  : biases fp32: b1[64] b2[64] b3[64] b4[16]
//   [23360, 23424)  : N_values fp32 [16]
//   [23424, 23488)  : level offsets fp32 [16] (prefix sum of N_l+1)
constexpr int WFRAG_HALFS = 22 * 64 * 8;   // 11264 halfs = 22528 B
constexpr int BIAS_FLOATS = 208;           // 3*64 + 16
constexpr int WS_BYTES    = 22528 + 240 * 4;   // 23488
constexpr int WS_UINT4    = WS_BYTES / 16;     // 1468
constexpr int MAX_STAGE   = 4224;          // >= sum(N_l+1) = 4179

// R6: H2 test (TLP) without R4's spills. 512 thr, VGPR<=128 via
// __launch_bounds__(512,4); LDS cut 128->74 KB (single sH/wave + f16-staged
// sV1/sV2) -> 2 blocks/CU = 4 waves/SIMD. Scattered-txn count UNCHANGED:
// this round isolates occupancy. Null result => L2 request-rate roofline (H1).
constexpr int BLK   = 512;                 // threads / block (8 waves)
constexpr int WAVES = 8;
constexpr int PTS_PER_BLOCK = 1024;        // 8 waves x 8 tiles x 16 pts

struct Meta { float n[16]; float off[16]; };

// ---------------- prep: swizzle weights into MFMA fragment order ----------------
__global__ void prep_weights(const float* __restrict__ W1, const float* __restrict__ b1,
                             const float* __restrict__ W2, const float* __restrict__ b2,
                             const float* __restrict__ W3, const float* __restrict__ b3,
                             const float* __restrict__ W4, const float* __restrict__ b4,
                             _Float16* __restrict__ wsW, float* __restrict__ wsB, Meta mv)
{
    const int tid = threadIdx.x;
    if (blockIdx.x < 44) {
        // A'-fragment: lane l holds W[k = 32s + 8*(l>>4) + j][n = 16t + (l&15)]
        const int e = blockIdx.x * 256 + tid;       // 44*256 == WFRAG_HALFS exactly
        const int frag = e >> 9;
        const int l    = (e >> 3) & 63;
        const int j    = e & 7;
        const int g = l >> 4, m = l & 15;
        float v;
        if (frag < 4) {                       // L1: W1 (32x64), s=0, t=frag
            v = W1[(8*g + j) * 64 + 16*frag + m];
        } else if (frag < 12) {               // L2: W2 (64x64)
            const int s = (frag - 4) >> 2, t = (frag - 4) & 3;
            v = W2[(32*s + 8*g + j) * 64 + 16*t + m];
        } else if (frag < 20) {               // L3: W3 (64x64)
            const int s = (frag - 12) >> 2, t = (frag - 12) & 3;
            v = W3[(32*s + 8*g + j) * 64 + 16*t + m];
        } else {                              // L4: W4 (64x3), pad n>=3 with 0
            const int s = frag - 20;
            v = (m < 3) ? W4[(32*s + 8*g + j) * 3 + m] : 0.f;
        }
        wsW[e] = (_Float16)v;
    } else {
        if (tid < 64) { wsB[tid] = b1[tid]; wsB[64 + tid] = b2[tid]; wsB[128 + tid] = b3[tid]; }
        else if (tid < 80)  { const int r = tid - 64; wsB[192 + r] = (r < 3) ? b4[r] : 0.f; }
        else if (tid < 96)  wsB[BIAS_FLOATS + (tid - 80)] = mv.n[tid - 80];
        else if (tid < 112) wsB[BIAS_FLOATS + 16 + (tid - 96)] = mv.off[tid - 96];
    }
}

// ---------------- main fused kernel ----------------
// v2 = tl[xi]          : staged in LDS as f16x2 (xi <= N_l)
// v1 = tl[(yi*P)&MASK] : staged in LDS as f16x2 (yi-indexed)
// v3 = tl[(xi^yp)&MASK]: genuinely 2D-random -> pipelined VMEM gather (f32 exact)
#define DS_FENCE() __asm__ volatile("s_waitcnt lgkmcnt(0)" ::: "memory")

__device__ __forceinline__ void issue_v3(float2 (&v3)[4], const float2 xy,
                                         const float2* __restrict__ table,
                                         const float (&nvq)[4], const int g)
{
    #pragma unroll
    for (int q = 0; q < 4; ++q) {
        const float n = nvq[q];
        const float xs = xy.x * n, ys = xy.y * n;
        const unsigned xi = (unsigned)(int)floorf(xs);
        const unsigned yi = (unsigned)(int)floorf(ys);
        v3[q] = table[(size_t)(4*g + q) * T_ + ((xi ^ (yi * PRIME)) & TMASK)];
    }
}

__device__ __forceinline__ half8 make_feat(const float2 xy, const float2 (&v3)[4],
                                           const float (&nvq)[4], const int (&offq)[4],
                                           const half2v* __restrict__ sV1,
                                           const half2v* __restrict__ sV2,
                                           const float2 (&v0c)[4])
{
    half8 feat;
    #pragma unroll
    for (int q = 0; q < 4; ++q) {
        const float n = nvq[q];
        const float xs = xy.x * n, ys = xy.y * n;
        const float xf = floorf(xs), yf = floorf(ys);
        const float fx = xs - xf, fy = ys - yf;
        const int xi = (int)xf, yi = (int)yf;
        const half2v v1h = sV1[offq[q] + yi];
        const half2v v2h = sV2[offq[q] + xi];
        const float cx = 1.f - fx, cy = 1.f - fy;
        const float w0 = cx*cy, w1 = cx*fy, w2 = fx*cy, w3 = fx*fy;
        feat[2*q+0] = (_Float16)(w0*v0c[q].x + w1*(float)v1h[0] + w2*(float)v2h[0] + w3*v3[q].x);
        feat[2*q+1] = (_Float16)(w0*v0c[q].y + w1*(float)v1h[1] + w2*(float)v2h[1] + w3*v3[q].y);
    }
    return feat;
}

// leaky-relu + f16-pack + H write for one output tile t
__device__ __forceinline__ void act_store(_Float16* __restrict__ H, const int c,
                                          const int g, const int t, const float4v acc)
{
    union { _Float16 h[4]; float2 f2; } u;
    #pragma unroll
    for (int r = 0; r < 4; ++r) {
        const float v = acc[r];
        u.h[r] = (_Float16)(v > 0.f ? v : 0.01f * v);
    }
    *(float2*)(H + c*HP + 16*t + 4*g) = u.f2;
}

__global__ __launch_bounds__(BLK, 4)
void fused_hashnerf_mfma(const float2* __restrict__ X,
                         const float2* __restrict__ table,
                         const uint4* __restrict__ ws,
                         float* __restrict__ out)
{
    __shared__ uint4    sRaw[WS_UINT4];        // W frags (f16) + biases + meta  (23.5 KB)
    __shared__ _Float16 sH[WAVES][16 * HP];    // per-wave activation buffer     (18.4 KB)
    __shared__ half2v   sV1[MAX_STAGE];        // tl[(i*PRIME)&TMASK] f16, yi-idx (16.9 KB)
    __shared__ half2v   sV2[MAX_STAGE];        // tl[i] f16, xi-indexed           (16.9 KB)

    const int tid = threadIdx.x;
    for (int i = tid; i < WS_UINT4; i += BLK) sRaw[i] = ws[i];
    __syncthreads();

    const _Float16* Wl = (const _Float16*)sRaw;
    const float*    Bl = (const float*)(sRaw + (22528 / 16));

    // ---- stage per-level v1/v2 tables into LDS (f16) ----
    {
        const float* NVp = Bl + BIAS_FLOATS;
        const float* OFp = Bl + BIAS_FLOATS + 16;
        for (int l = 0; l < 16; ++l) {
            const int nl  = (int)NVp[l];
            const int off = (int)OFp[l];
            const float2* tl = table + (size_t)l * T_;
            for (int i = tid; i <= nl; i += BLK) {
                const float2 a = tl[i];                              // coalesced
                const float2 b = tl[((unsigned)i * PRIME) & TMASK];  // scattered, amortized
                sV2[off + i] = half2v{(_Float16)a.x, (_Float16)a.y};
                sV1[off + i] = half2v{(_Float16)b.x, (_Float16)b.y};
            }
        }
    }
    __syncthreads();

    const int wave = tid >> 6, lane = tid & 63;
    const int g = lane >> 4, c = lane & 15;
    _Float16* H = &sH[wave][0];

    // loop-invariant bias fragments: C'[n_out = 16t + 4g + r][pt]
    float4v b1f[4], b2f[4], b3f[4], b4f;
    #pragma unroll
    for (int t = 0; t < 4; ++t) {
        b1f[t] = *(const float4v*)(Bl +       16*t + 4*g);
        b2f[t] = *(const float4v*)(Bl +  64 + 16*t + 4*g);
        b3f[t] = *(const float4v*)(Bl + 128 + 16*t + 4*g);
    }
    b4f = *(const float4v*)(Bl + 192 + 4*g);
    float nvq[4];
    int   offq[4];
    #pragma unroll
    for (int q = 0; q < 4; ++q) {
        nvq[q]  = Bl[BIAS_FLOATS + 4*g + q];
        offq[q] = (int)Bl[BIAS_FLOATS + 16 + 4*g + q];
    }

    const int base_pt = blockIdx.x * PTS_PER_BLOCK + wave * 128;

    // X for all 8 tiles (coalesced, static indices after unroll)
    float2 xy[8];
    #pragma unroll
    for (int it = 0; it < 8; ++it) xy[it] = X[base_pt + it*16 + c];

    // per-level constant corner (0,0): v0 = table[lv*T + 0] (f32, exact)
    float2 v0c[4];
    #pragma unroll
    for (int q = 0; q < 4; ++q) v0c[q] = table[(size_t)(4*g + q) * T_];

    float2 GA[4], GB[4];
    issue_v3(GA, xy[0], table, nvq, g);        // prologue: tile 0 in flight

    #pragma unroll
    for (int it = 0; it < 8; ++it) {
        float2 (&Gc)[4] = (it & 1) ? GB : GA;  // static after unroll
        float2 (&Gn)[4] = (it & 1) ? GA : GB;

        // ---- consume tile it (vmcnt wait for v3 lands here) ----
        const half8 feat = make_feat(xy[it], Gc, nvq, offq, sV1, sV2, v0c);

        // ---- issue tile it+1's v3 gathers; they fly during the MLP below ----
        if (it < 7) issue_v3(Gn, xy[it+1], table, nvq, g);
        __builtin_amdgcn_sched_barrier(0);

        // ---- L1 ----
        float4v acc[4];
        #pragma unroll
        for (int t = 0; t < 4; ++t) {
            const half8 wf = *(const half8*)(Wl + (t*64 + lane)*8);
            acc[t] = __builtin_amdgcn_mfma_f32_16x16x32_f16(wf, feat, b1f[t], 0, 0, 0);
        }
        #pragma unroll
        for (int t = 0; t < 4; ++t) act_store(H, c, g, t, acc[t]);
        DS_FENCE();

        // ---- L2 ----
        half8 a0 = *(const half8*)(H + c*HP +      8*g);
        half8 a1 = *(const half8*)(H + c*HP + 32 + 8*g);
        #pragma unroll
        for (int t = 0; t < 4; ++t) {
            const half8 w0f = *(const half8*)(Wl + ((4 + t)*64 + lane)*8);
            const half8 w1f = *(const half8*)(Wl + ((8 + t)*64 + lane)*8);
            float4v a = __builtin_amdgcn_mfma_f32_16x16x32_f16(w0f, a0, b2f[t], 0, 0, 0);
            acc[t]    = __builtin_amdgcn_mfma_f32_16x16x32_f16(w1f, a1, a,      0, 0, 0);
        }
        #pragma unroll
        for (int t = 0; t < 4; ++t) act_store(H, c, g, t, acc[t]);
        DS_FENCE();

        // ---- L3 ----
        a0 = *(const half8*)(H + c*HP +      8*g);
        a1 = *(const half8*)(H + c*HP + 32 + 8*g);
        #pragma unroll
        for (int t = 0; t < 4; ++t) {
            const half8 w0f = *(const half8*)(Wl + ((12 + t)*64 + lane)*8);
            const half8 w1f = *(const half8*)(Wl + ((16 + t)*64 + lane)*8);
            float4v a = __builtin_amdgcn_mfma_f32_16x16x32_f16(w0f, a0, b3f[t], 0, 0, 0);
            acc[t]    = __builtin_amdgcn_mfma_f32_16x16x32_f16(w1f, a1, a,      0, 0, 0);
        }
        #pragma unroll
        for (int t = 0; t < 4; ++t) act_store(H, c, g, t, acc[t]);
        DS_FENCE();

        // ---- L4: n_out = 0..2 live in lanes g==0 ----
        a0 = *(const half8*)(H + c*HP +      8*g);
        a1 = *(const half8*)(H + c*HP + 32 + 8*g);
        const half8 w40 = *(const half8*)(Wl + (20*64 + lane)*8);
        const half8 w41 = *(const half8*)(Wl + (21*64 + lane)*8);
        float4v o = __builtin_amdgcn_mfma_f32_16x16x32_f16(w40, a0, b4f, 0, 0, 0);
        o         = __builtin_amdgcn_mfma_f32_16x16x32_f16(w41, a1, o,   0, 0, 0);
        if (g == 0) {
            float* op = out + (size_t)3 * (base_pt + it * 16 + c);
            op[0] = fmaxf(o[0], 0.f);
            op[1] = fmaxf(o[1], 0.f);
            op[2] = fmaxf(o[2], 0.f);
        }
    }
}

extern "C" void kernel_launch(void* const* d_in, const int* in_sizes, int n_in,
                              void* d_out, int out_size, void* d_ws, size_t ws_size,
                              hipStream_t stream) {
    const float2* X     = (const float2*)d_in[0];
    const float2* table = (const float2*)d_in[1];
    const float*  W1    = (const float*)d_in[2];
    const float*  b1    = (const float*)d_in[3];
    const float*  W2    = (const float*)d_in[4];
    const float*  b2    = (const float*)d_in[5];
    const float*  W3    = (const float*)d_in[6];
    const float*  b3    = (const float*)d_in[7];
    const float*  W4    = (const float*)d_in[8];
    const float*  b4    = (const float*)d_in[9];
    float* out          = (float*)d_out;

    const int npts = in_sizes[0] / 2;

    // N_l = floor(float32(16 * b^l)), b computed in double (matches numpy);
    // off[l] = prefix sum of (N_l + 1) for the staged LDS tables.
    Meta mv;
    const double bg = exp((log(1024.0) - log(16.0)) / 15.0);
    int acc = 0;
    for (int l = 0; l < 16; ++l) {
        const float nl = floorf((float)(16.0 * pow(bg, (double)l)));
        mv.n[l]   = nl;
        mv.off[l] = (float)acc;
        acc += (int)nl + 1;
    }

    _Float16* wsW = (_Float16*)d_ws;
    float*    wsB = (float*)((char*)d_ws + 22528);

    prep_weights<<<45, 256, 0, stream>>>(W1, b1, W2, b2, W3, b3, W4, b4, wsW, wsB, mv);
    fused_hashnerf_mfma<<<npts / PTS_PER_BLOCK, BLK, 0, stream>>>(X, table, (const uint4*)d_ws, out);
}

// Round 7
// 215.529 us; speedup vs baseline: 1.0745x; 1.0745x over previous
//
#include <hip/hip_runtime.h>
#include <math.h>

typedef _Float16 half8  __attribute__((ext_vector_type(8)));
typedef _Float16 half2v __attribute__((ext_vector_type(2)));
typedef float    float4v __attribute__((ext_vector_type(4)));

constexpr int T_ = 1 << 18;            // hash table size per level
constexpr unsigned TMASK = T_ - 1;
constexpr unsigned PRIME = 2654435761u;
constexpr int HP = 72;                 // H row pitch in f16 (64 + 8 pad: bank-spread)

// ws layout:
//   [0, 22528)      : 22 W-fragments (f16), frag f: 64 lanes x 8 halfs
//   [22528, 23360)  : biases fp32: b1[64] b2[64] b3[64] b4[16]
//   [23360, 23424)  : N_values fp32 [16]
//   [23424, 23488)  : level offsets fp32 [16] (prefix sum of N_l+1)
constexpr int WFRAG_HALFS = 22 * 64 * 8;   // 11264 halfs = 22528 B
constexpr int BIAS_FLOATS = 208;           // 3*64 + 16
constexpr int WS_BYTES    = 22528 + 240 * 4;   // 23488
constexpr int WS_UINT4    = WS_BYTES / 16;     // 1468
constexpr int MAX_STAGE   = 4224;          // >= sum(N_l+1) = 4179

// R7: clean occupancy (H2) test. R6's __launch_bounds__(512,4) made hipcc cap
// VGPR at 64 -> spills (WRITE_SIZE 80 MB) that confounded the doubled
// occupancy. This round: IDENTICAL kernel, plain __launch_bounds__(512).
// Structure compiles to ~92-96 VGPR (R3/R5 evidence) <= 128, so both
// 75.8 KB-LDS blocks co-reside (151.6 <= 160 KB) at 4 waves/SIMD, no spills.
constexpr int BLK   = 512;                 // threads / block (8 waves)
constexpr int WAVES = 8;
constexpr int PTS_PER_BLOCK = 1024;        // 8 waves x 8 tiles x 16 pts

struct Meta { float n[16]; float off[16]; };

// ---------------- prep: swizzle weights into MFMA fragment order ----------------
__global__ void prep_weights(const float* __restrict__ W1, const float* __restrict__ b1,
                             const float* __restrict__ W2, const float* __restrict__ b2,
                             const float* __restrict__ W3, const float* __restrict__ b3,
                             const float* __restrict__ W4, const float* __restrict__ b4,
                             _Float16* __restrict__ wsW, float* __restrict__ wsB, Meta mv)
{
    const int tid = threadIdx.x;
    if (blockIdx.x < 44) {
        // A'-fragment: lane l holds W[k = 32s + 8*(l>>4) + j][n = 16t + (l&15)]
        const int e = blockIdx.x * 256 + tid;       // 44*256 == WFRAG_HALFS exactly
        const int frag = e >> 9;
        const int l    = (e >> 3) & 63;
        const int j    = e & 7;
        const int g = l >> 4, m = l & 15;
        float v;
        if (frag < 4) {                       // L1: W1 (32x64), s=0, t=frag
            v = W1[(8*g + j) * 64 + 16*frag + m];
        } else if (frag < 12) {               // L2: W2 (64x64)
            const int s = (frag - 4) >> 2, t = (frag - 4) & 3;
            v = W2[(32*s + 8*g + j) * 64 + 16*t + m];
        } else if (frag < 20) {               // L3: W3 (64x64)
            const int s = (frag - 12) >> 2, t = (frag - 12) & 3;
            v = W3[(32*s + 8*g + j) * 64 + 16*t + m];
        } else {                              // L4: W4 (64x3), pad n>=3 with 0
            const int s = frag - 20;
            v = (m < 3) ? W4[(32*s + 8*g + j) * 3 + m] : 0.f;
        }
        wsW[e] = (_Float16)v;
    } else {
        if (tid < 64) { wsB[tid] = b1[tid]; wsB[64 + tid] = b2[tid]; wsB[128 + tid] = b3[tid]; }
        else if (tid < 80)  { const int r = tid - 64; wsB[192 + r] = (r < 3) ? b4[r] : 0.f; }
        else if (tid < 96)  wsB[BIAS_FLOATS + (tid - 80)] = mv.n[tid - 80];
        else if (tid < 112) wsB[BIAS_FLOATS + 16 + (tid - 96)] = mv.off[tid - 96];
    }
}

// ---------------- main fused kernel ----------------
// v2 = tl[xi]          : staged in LDS as f16x2 (xi <= N_l)
// v1 = tl[(yi*P)&MASK] : staged in LDS as f16x2 (yi-indexed)
// v3 = tl[(xi^yp)&MASK]: genuinely 2D-random -> pipelined VMEM gather (f32 exact)
#define DS_FENCE() __asm__ volatile("s_waitcnt lgkmcnt(0)" ::: "memory")

__device__ __forceinline__ void issue_v3(float2 (&v3)[4], const float2 xy,
                                         const float2* __restrict__ table,
                                         const float (&nvq)[4], const int g)
{
    #pragma unroll
    for (int q = 0; q < 4; ++q) {
        const float n = nvq[q];
        const float xs = xy.x * n, ys = xy.y * n;
        const unsigned xi = (unsigned)(int)floorf(xs);
        const unsigned yi = (unsigned)(int)floorf(ys);
        v3[q] = table[(size_t)(4*g + q) * T_ + ((xi ^ (yi * PRIME)) & TMASK)];
    }
}

__device__ __forceinline__ half8 make_feat(const float2 xy, const float2 (&v3)[4],
                                           const float (&nvq)[4], const int (&offq)[4],
                                           const half2v* __restrict__ sV1,
                                           const half2v* __restrict__ sV2,
                                           const float2 (&v0c)[4])
{
    half8 feat;
    #pragma unroll
    for (int q = 0; q < 4; ++q) {
        const float n = nvq[q];
        const float xs = xy.x * n, ys = xy.y * n;
        const float xf = floorf(xs), yf = floorf(ys);
        const float fx = xs - xf, fy = ys - yf;
        const int xi = (int)xf, yi = (int)yf;
        const half2v v1h = sV1[offq[q] + yi];
        const half2v v2h = sV2[offq[q] + xi];
        const float cx = 1.f - fx, cy = 1.f - fy;
        const float w0 = cx*cy, w1 = cx*fy, w2 = fx*cy, w3 = fx*fy;
        feat[2*q+0] = (_Float16)(w0*v0c[q].x + w1*(float)v1h[0] + w2*(float)v2h[0] + w3*v3[q].x);
        feat[2*q+1] = (_Float16)(w0*v0c[q].y + w1*(float)v1h[1] + w2*(float)v2h[1] + w3*v3[q].y);
    }
    return feat;
}

// leaky-relu + f16-pack + H write for one output tile t
__device__ __forceinline__ void act_store(_Float16* __restrict__ H, const int c,
                                          const int g, const int t, const float4v acc)
{
    union { _Float16 h[4]; float2 f2; } u;
    #pragma unroll
    for (int r = 0; r < 4; ++r) {
        const float v = acc[r];
        u.h[r] = (_Float16)(v > 0.f ? v : 0.01f * v);
    }
    *(float2*)(H + c*HP + 16*t + 4*g) = u.f2;
}

__global__ __launch_bounds__(BLK)
void fused_hashnerf_mfma(const float2* __restrict__ X,
                         const float2* __restrict__ table,
                         const uint4* __restrict__ ws,
                         float* __restrict__ out)
{
    __shared__ uint4    sRaw[WS_UINT4];        // W frags (f16) + biases + meta  (23.5 KB)
    __shared__ _Float16 sH[WAVES][16 * HP];    // per-wave activation buffer     (18.4 KB)
    __shared__ half2v   sV1[MAX_STAGE];        // tl[(i*PRIME)&TMASK] f16, yi-idx (16.9 KB)
    __shared__ half2v   sV2[MAX_STAGE];        // tl[i] f16, xi-indexed           (16.9 KB)

    const int tid = threadIdx.x;
    for (int i = tid; i < WS_UINT4; i += BLK) sRaw[i] = ws[i];
    __syncthreads();

    const _Float16* Wl = (const _Float16*)sRaw;
    const float*    Bl = (const float*)(sRaw + (22528 / 16));

    // ---- stage per-level v1/v2 tables into LDS (f16) ----
    {
        const float* NVp = Bl + BIAS_FLOATS;
        const float* OFp = Bl + BIAS_FLOATS + 16;
        for (int l = 0; l < 16; ++l) {
            const int nl  = (int)NVp[l];
            const int off = (int)OFp[l];
            const float2* tl = table + (size_t)l * T_;
            for (int i = tid; i <= nl; i += BLK) {
                const float2 a = tl[i];                              // coalesced
                const float2 b = tl[((unsigned)i * PRIME) & TMASK];  // scattered, amortized
                sV2[off + i] = half2v{(_Float16)a.x, (_Float16)a.y};
                sV1[off + i] = half2v{(_Float16)b.x, (_Float16)b.y};
            }
        }
    }
    __syncthreads();

    const int wave = tid >> 6, lane = tid & 63;
    const int g = lane >> 4, c = lane & 15;
    _Float16* H = &sH[wave][0];

    // loop-invariant bias fragments: C'[n_out = 16t + 4g + r][pt]
    float4v b1f[4], b2f[4], b3f[4], b4f;
    #pragma unroll
    for (int t = 0; t < 4; ++t) {
        b1f[t] = *(const float4v*)(Bl +       16*t + 4*g);
        b2f[t] = *(const float4v*)(Bl +  64 + 16*t + 4*g);
        b3f[t] = *(const float4v*)(Bl + 128 + 16*t + 4*g);
    }
    b4f = *(const float4v*)(Bl + 192 + 4*g);
    float nvq[4];
    int   offq[4];
    #pragma unroll
    for (int q = 0; q < 4; ++q) {
        nvq[q]  = Bl[BIAS_FLOATS + 4*g + q];
        offq[q] = (int)Bl[BIAS_FLOATS + 16 + 4*g + q];
    }

    const int base_pt = blockIdx.x * PTS_PER_BLOCK + wave * 128;

    // X for all 8 tiles (coalesced, static indices after unroll)
    float2 xy[8];
    #pragma unroll
    for (int it = 0; it < 8; ++it) xy[it] = X[base_pt + it*16 + c];

    // per-level constant corner (0,0): v0 = table[lv*T + 0] (f32, exact)
    float2 v0c[4];
    #pragma unroll
    for (int q = 0; q < 4; ++q) v0c[q] = table[(size_t)(4*g + q) * T_];

    float2 GA[4], GB[4];
    issue_v3(GA, xy[0], table, nvq, g);        // prologue: tile 0 in flight

    #pragma unroll
    for (int it = 0; it < 8; ++it) {
        float2 (&Gc)[4] = (it & 1) ? GB : GA;  // static after unroll
        float2 (&Gn)[4] = (it & 1) ? GA : GB;

        // ---- consume tile it (vmcnt wait for v3 lands here) ----
        const half8 feat = make_feat(xy[it], Gc, nvq, offq, sV1, sV2, v0c);

        // ---- issue tile it+1's v3 gathers; they fly during the MLP below ----
        if (it < 7) issue_v3(Gn, xy[it+1], table, nvq, g);
        __builtin_amdgcn_sched_barrier(0);

        // ---- L1 ----
        float4v acc[4];
        #pragma unroll
        for (int t = 0; t < 4; ++t) {
            const half8 wf = *(const half8*)(Wl + (t*64 + lane)*8);
            acc[t] = __builtin_amdgcn_mfma_f32_16x16x32_f16(wf, feat, b1f[t], 0, 0, 0);
        }
        #pragma unroll
        for (int t = 0; t < 4; ++t) act_store(H, c, g, t, acc[t]);
        DS_FENCE();

        // ---- L2 ----
        half8 a0 = *(const half8*)(H + c*HP +      8*g);
        half8 a1 = *(const half8*)(H + c*HP + 32 + 8*g);
        #pragma unroll
        for (int t = 0; t < 4; ++t) {
            const half8 w0f = *(const half8*)(Wl + ((4 + t)*64 + lane)*8);
            const half8 w1f = *(const half8*)(Wl + ((8 + t)*64 + lane)*8);
            float4v a = __builtin_amdgcn_mfma_f32_16x16x32_f16(w0f, a0, b2f[t], 0, 0, 0);
            acc[t]    = __builtin_amdgcn_mfma_f32_16x16x32_f16(w1f, a1, a,      0, 0, 0);
        }
        #pragma unroll
        for (int t = 0; t < 4; ++t) act_store(H, c, g, t, acc[t]);
        DS_FENCE();

        // ---- L3 ----
        a0 = *(const half8*)(H + c*HP +      8*g);
        a1 = *(const half8*)(H + c*HP + 32 + 8*g);
        #pragma unroll
        for (int t = 0; t < 4; ++t) {
            const half8 w0f = *(const half8*)(Wl + ((12 + t)*64 + lane)*8);
            const half8 w1f = *(const half8*)(Wl + ((16 + t)*64 + lane)*8);
            float4v a = __builtin_amdgcn_mfma_f32_16x16x32_f16(w0f, a0, b3f[t], 0, 0, 0);
            acc[t]    = __builtin_amdgcn_mfma_f32_16x16x32_f16(w1f, a1, a,      0, 0, 0);
        }
        #pragma unroll
        for (int t = 0; t < 4; ++t) act_store(H, c, g, t, acc[t]);
        DS_FENCE();

        // ---- L4: n_out = 0..2 live in lanes g==0 ----
        a0 = *(const half8*)(H + c*HP +      8*g);
        a1 = *(const half8*)(H + c*HP + 32 + 8*g);
        const half8 w40 = *(const half8*)(Wl + (20*64 + lane)*8);
        const half8 w41 = *(const half8*)(Wl + (21*64 + lane)*8);
        float4v o = __builtin_amdgcn_mfma_f32_16x16x32_f16(w40, a0, b4f, 0, 0, 0);
        o         = __builtin_amdgcn_mfma_f32_16x16x32_f16(w41, a1, o,   0, 0, 0);
        if (g == 0) {
            float* op = out + (size_t)3 * (base_pt + it * 16 + c);
            op[0] = fmaxf(o[0], 0.f);
            op[1] = fmaxf(o[1], 0.f);
            op[2] = fmaxf(o[2], 0.f);
        }
    }
}

extern "C" void kernel_launch(void* const* d_in, const int* in_sizes, int n_in,
                              void* d_out, int out_size, void* d_ws, size_t ws_size,
                              hipStream_t stream) {
    const float2* X     = (const float2*)d_in[0];
    const float2* table = (const float2*)d_in[1];
    const float*  W1    = (const float*)d_in[2];
    const float*  b1    = (const float*)d_in[3];
    const float*  W2    = (const float*)d_in[4];
    const float*  b2    = (const float*)d_in[5];
    const float*  W3    = (const float*)d_in[6];
    const float*  b3    = (const float*)d_in[7];
    const float*  W4    = (const float*)d_in[8];
    const float*  b4    = (const float*)d_in[9];
    float* out          = (float*)d_out;

    const int npts = in_sizes[0] / 2;

    // N_l = floor(float32(16 * b^l)), b computed in double (matches numpy);
    // off[l] = prefix sum of (N_l + 1) for the staged LDS tables.
    Meta mv;
    const double bg = exp((log(1024.0) - log(16.0)) / 15.0);
    int acc = 0;
    for (int l = 0; l < 16; ++l) {
        const float nl = floorf((float)(16.0 * pow(bg, (double)l)));
        mv.n[l]   = nl;
        mv.off[l] = (float)acc;
        acc += (int)nl + 1;
    }

    _Float16* wsW = (_Float16*)d_ws;
    float*    wsB = (float*)((char*)d_ws + 22528);

    prep_weights<<<45, 256, 0, stream>>>(W1, b1, W2, b2, W3, b3, W4, b4, wsW, wsB, mv);
    fused_hashnerf_mfma<<<npts / PTS_PER_BLOCK, BLK, 0, stream>>>(X, table, (const uint4*)d_ws, out);
}